// Round 5
// baseline (765.089 us; speedup 1.0000x reference)
//
#include <hip/hip_runtime.h>
#include <math.h>

// Problem constants: E=8, D=1024, H=4096, K=2, B=2, S=2048
#define NE 8
#define DD 1024
#define HH 4096
#define TT 4096          // B*S tokens
#define RR 8192          // TT * K rows

typedef __attribute__((ext_vector_type(8))) short short8;   // 8 bf16 (4 VGPRs)
typedef __attribute__((ext_vector_type(4))) float f32x4;    // MFMA C/D frag

__device__ __forceinline__ unsigned short f2bf(float f) {
    unsigned int u = __float_as_uint(f);
    u += 0x7fffu + ((u >> 16) & 1u);   // RNE
    return (unsigned short)(u >> 16);
}

// Fast GELU (exact-erf form): A&S 7.1.26 branchless erf, max |err| 1.5e-7 —
// far below the bf16 quantization of hbuf. ~13 VALU ops vs ~30 for libm erff.
__device__ __forceinline__ float gelu_fast(float v) {
    float z = fabsf(v) * 0.70710678f;
    float t = __fdividef(1.0f, fmaf(0.3275911f, z, 1.0f));
    float p = fmaf(1.061405429f, t, -1.453152027f);
    p = fmaf(p, t, 1.421413741f);
    p = fmaf(p, t, -0.284496736f);
    p = fmaf(p, t, 0.254829592f);
    p = p * t;
    float erf = fmaf(-p, __expf(-z * z), 1.0f);
    return 0.5f * v * (1.0f + copysignf(erf, v));
}

// async global->LDS, 16B per lane; LDS dest = wave-uniform base + lane*16.
__device__ __forceinline__ void async_copy16(void* lds, const void* g) {
    auto* lp = reinterpret_cast<__attribute__((address_space(3))) unsigned int*>(
        (unsigned int)(unsigned long long)(lds));
    auto* gp = reinterpret_cast<const __attribute__((address_space(1))) unsigned int*>(
        (unsigned long long)(g));
    __builtin_amdgcn_global_load_lds(gp, lp, 16, 0, 0);
}

// ---------------- ws layout (bytes) ----------------
// 0: counts[8]   64: offs[9]   128: cursor[8]
// 4096   : topk_e  [RR] int
// 36864  : topk_p  [RR] float
// 69632  : row_token[RR] int
// 102400 : slot_of [RR] int
// 1MB    : xb  [TT*DD] bf16 (8MB)   -- yp [RR*DD] f32 (32MB) aliases [1,33) after gemm1
// 9MB    : w1s [E][H*D] bf16 swizzled (64MB)  (first 24MB also dead after gemm1)
// 73MB   : w2s [E][D*H] bf16 swizzled (64MB)
// 137MB  : hbuf[RR*HH] bf16 (64MB)              total 201MB

// ---------- x -> bf16 ----------
__global__ void cvtx_kernel(const float* __restrict__ x, unsigned short* __restrict__ xb) {
    size_t i = (size_t)(blockIdx.x * 256 + threadIdx.x) * 4;
    float4 v = *(const float4*)&x[i];
    unsigned int lo = (unsigned int)f2bf(v.x) | ((unsigned int)f2bf(v.y) << 16);
    unsigned int hi = (unsigned int)f2bf(v.z) | ((unsigned int)f2bf(v.w) << 16);
    *(uint2*)&xb[i] = make_uint2(lo, hi);
}

// ---------- weight transpose+convert+swizzle ----------
// src [K][N] f32 -> dst swizzled bf16 panels: [nt=n>>7][kb=k>>5][q=(k>>3)&3][row=n&127][lo=k&7]
// grid (N/64, K/64, E), block 256
__global__ __launch_bounds__(256) void transpose_swz_kernel(const float* __restrict__ src,
        unsigned short* __restrict__ dst, int K, int N) {
    const int e = blockIdx.z;
    src += (size_t)e * K * N;
    dst += (size_t)e * K * N;
    const int c0 = blockIdx.x * 64;   // n base
    const int r0 = blockIdx.y * 64;   // k base
    __shared__ unsigned short t[64][65];
    const int tid = threadIdx.x;
    // read: float4 per thread along N, rows along K
    const int rc4 = (tid & 15) * 4, rr = tid >> 4;
    #pragma unroll
    for (int i = 0; i < 4; i++) {
        int r = rr + i * 16;
        float4 v = *(const float4*)&src[(size_t)(r0 + r) * N + c0 + rc4];
        t[r][rc4]     = f2bf(v.x);
        t[r][rc4 + 1] = f2bf(v.y);
        t[r][rc4 + 2] = f2bf(v.z);
        t[r][rc4 + 3] = f2bf(v.w);
    }
    __syncthreads();
    // write: per wave, one 16B chunk per lane (8 consecutive k for one n) -> 1KB contiguous
    const int n_local = tid & 63;
    const int n = c0 + n_local;
    const int nt = n >> 7, row = n & 127;
    const int Kdiv32 = K >> 5;
    #pragma unroll
    for (int it = 0; it < 2; it++) {
        int dg = (tid >> 6) + 4 * it;              // k-group of 8 within the 64-k tile
        int kb = 2 * blockIdx.y + (dg >> 2);
        int q = dg & 3;
        unsigned short tmp[8];
        #pragma unroll
        for (int i = 0; i < 8; i++) tmp[i] = t[dg * 8 + i][n_local];
        size_t idx = ((((size_t)nt * Kdiv32 + kb) * 4 + q) * 128 + row) * 8;
        *(uint4*)&dst[idx] = *(uint4*)&tmp[0];
    }
}

// ---------- router ----------
__global__ void router_kernel(const float* __restrict__ x, const float* __restrict__ rw,
                              const float* __restrict__ rb, float* __restrict__ logits_out,
                              int* __restrict__ topk_e, float* __restrict__ topk_p,
                              int* __restrict__ counts) {
    const int t = blockIdx.x;
    const int tid = threadIdx.x;
    float4 xv = *(const float4*)&x[(size_t)t * DD + tid * 4];
    const float* rwp = rw + (size_t)(tid * 4) * NE;
    float acc[NE];
    #pragma unroll
    for (int e = 0; e < NE; e++) acc[e] = 0.f;
    float xs[4] = {xv.x, xv.y, xv.z, xv.w};
    #pragma unroll
    for (int i = 0; i < 4; i++) {
        #pragma unroll
        for (int e = 0; e < NE; e++) acc[e] += xs[i] * rwp[i * NE + e];
    }
    #pragma unroll
    for (int e = 0; e < NE; e++) {
        float v = acc[e];
        for (int off = 32; off > 0; off >>= 1) v += __shfl_down(v, off);
        acc[e] = v;
    }
    __shared__ float part[4][NE];
    if ((tid & 63) == 0) {
        #pragma unroll
        for (int e = 0; e < NE; e++) part[tid >> 6][e] = acc[e];
    }
    __syncthreads();
    if (tid == 0) {
        float lg[NE];
        #pragma unroll
        for (int e = 0; e < NE; e++)
            lg[e] = part[0][e] + part[1][e] + part[2][e] + part[3][e] + rb[e];
        #pragma unroll
        for (int e = 0; e < NE; e++) logits_out[(size_t)t * NE + e] = lg[e];
        float m = lg[0];
        #pragma unroll
        for (int e = 1; e < NE; e++) m = fmaxf(m, lg[e]);
        float pr[NE];
        #pragma unroll
        for (int e = 0; e < NE; e++) pr[e] = __expf(lg[e] - m);
        int i0 = 0;
        #pragma unroll
        for (int e = 1; e < NE; e++) if (pr[e] > pr[i0]) i0 = e;
        int i1 = (i0 == 0) ? 1 : 0;
        #pragma unroll
        for (int e = 0; e < NE; e++) if (e != i0 && pr[e] > pr[i1]) i1 = e;
        float p0 = pr[i0], p1 = pr[i1];
        float inv = 1.f / (p0 + p1);
        topk_e[t * 2] = i0;  topk_e[t * 2 + 1] = i1;
        topk_p[t * 2] = p0 * inv;  topk_p[t * 2 + 1] = p1 * inv;
        atomicAdd(&counts[i0], 1);
        atomicAdd(&counts[i1], 1);
    }
}

__global__ void prefix_kernel(const int* __restrict__ counts, int* __restrict__ offs,
                              int* __restrict__ cursor) {
    if (threadIdx.x == 0) {
        int a = 0;
        for (int e = 0; e < NE; e++) { offs[e] = a; cursor[e] = a; a += counts[e]; }
        offs[NE] = a;
    }
}

__global__ void scatter_kernel(const int* __restrict__ topk_e, int* __restrict__ cursor,
                               int* __restrict__ row_token, int* __restrict__ slot_of) {
    int i = blockIdx.x * 256 + threadIdx.x;   // i = t*2+k
    int e = topk_e[i];
    int pos = atomicAdd(&cursor[e], 1);
    row_token[pos] = i >> 1;
    slot_of[i] = pos;
}

// ---------- shared MFMA compute step (one BK=32 tile from one LDS buffer) ----------
__device__ __forceinline__ void mfma_step(const unsigned short* Ab, const unsigned short* Bb,
        int wr, int wc, int m16, int q, f32x4 (&acc)[4][4]) {
    short8 af[4], bfr[4];
    #pragma unroll
    for (int i = 0; i < 4; i++) af[i] = *(const short8*)&Ab[q * 1024 + (wr + i * 16 + m16) * 8];
    #pragma unroll
    for (int j = 0; j < 4; j++) bfr[j] = *(const short8*)&Bb[q * 1024 + (wc + j * 16 + m16) * 8];
    #pragma unroll
    for (int i = 0; i < 4; i++)
        #pragma unroll
        for (int j = 0; j < 4; j++)
            acc[i][j] = __builtin_amdgcn_mfma_f32_16x16x32_bf16(af[i], bfr[j], acc[i][j], 0, 0, 0);
}

// ---------- 3-stage pipelined K-loop (T3+T4: counted vmcnt, raw barriers) ----------
// Tile t lives in buffer t%3. Per tile each thread issues 4 global_load_lds.
// Steady state keeps 2 tiles (8 loads) in flight across barriers; vmcnt never 0 in loop.
// Correctness: stage(t+2) targets buf (t-1)%3, freed by the previous iteration's
// post-compute barrier; per-wave vmcnt(8) (FIFO, so tile t's loads done) + s_barrier
// makes completion block-wide before any ds_read. NK >= 3.
template <int NK>
__device__ __forceinline__ void kloop_3s(
        const unsigned short* ag0, const unsigned short* ag1, const unsigned short* bg,
        unsigned short* As, unsigned short* Bs,   // each [3][4096] shorts, buf stride 4096
        int wv, int lane, int wr, int wc, int m16, int q, f32x4 (&acc)[4][4]) {
    unsigned short* alA = As + wv * 1024 + lane * 8;
    unsigned short* blB = Bs + wv * 1024 + lane * 8;

    // prologue: stage tiles 0,1 -> buf0,1 (8 loads in flight)
    #pragma unroll
    for (int p = 0; p < 2; ++p) {
        async_copy16(alA + p * 4096, ag0); async_copy16(alA + p * 4096 + 512, ag1);
        async_copy16(blB + p * 4096, bg);  async_copy16(blB + p * 4096 + 512, bg + 512);
        ag0 += 32; ag1 += 32; bg += 4096;
    }

    int cOff = 0;            // (t%3)*4096
    int sOff = 2 * 4096;     // ((t+2)%3)*4096
    #pragma unroll 1
    for (int t = 0; t < NK - 2; ++t) {
        async_copy16(alA + sOff, ag0); async_copy16(alA + sOff + 512, ag1);
        async_copy16(blB + sOff, bg);  async_copy16(blB + sOff + 512, bg + 512);
        ag0 += 32; ag1 += 32; bg += 4096;
        asm volatile("s_waitcnt vmcnt(8)" ::: "memory");   // tile t landed (2 tiles in flight)
        __builtin_amdgcn_s_barrier();
        mfma_step(As + cOff, Bs + cOff, wr, wc, m16, q, acc);
        __builtin_amdgcn_s_barrier();                      // all waves done reading buf t%3
        sOff = cOff;                                       // (t+3)%3 == t%3
        cOff += 4096; if (cOff == 3 * 4096) cOff = 0;      // (t+1)%3
    }
    // tail: tiles NK-2 (buf cOff), NK-1 already staged; drain 4 -> 0
    asm volatile("s_waitcnt vmcnt(4)" ::: "memory");
    __builtin_amdgcn_s_barrier();
    mfma_step(As + cOff, Bs + cOff, wr, wc, m16, q, acc);
    cOff += 4096; if (cOff == 3 * 4096) cOff = 0;
    asm volatile("s_waitcnt vmcnt(0)" ::: "memory");
    __builtin_amdgcn_s_barrier();
    mfma_step(As + cOff, Bs + cOff, wr, wc, m16, q, acc);
}

// ---------- GEMM1: h = gelu(X_e @ w1[e] + b1[e]) ----------
// tile 128x128, BK=32, 3-stage pipelined staging.
// 1-D grid 8192 with bijective XCD-grouping decode: the 8 blocks sharing one
// gathered A-panel (same rt,e; nt = nth*8+m, m=0..7) land on the same XCD (T1).
__global__ __launch_bounds__(256) void gemm1_kernel(
        const unsigned short* __restrict__ xb, const unsigned short* __restrict__ w1s,
        const float* __restrict__ b1, const int* __restrict__ offs,
        const int* __restrict__ row_token, unsigned short* __restrict__ hbuf) {
    const int bid = blockIdx.x;
    const int xcd = bid & 7;
    const int mem = (bid >> 3) & 7;
    const int g   = (bid >> 6) * 8 + xcd;   // [0,1024) bijective
    const int nth = g & 3;
    const int rt  = (g >> 2) & 31;
    const int e   = g >> 7;
    const int nt  = nth * 8 + mem;

    const int r0 = offs[e];
    const int ne = offs[e + 1] - r0;
    if (rt * 128 >= ne) return;

    __shared__ __align__(16) unsigned short As[3][4096];
    __shared__ __align__(16) unsigned short Bs[3][4096];

    const int tid = threadIdx.x;
    const int lane = tid & 63;
    const int wv = tid >> 6;
    const int wr = (wv >> 1) * 64, wc = (wv & 1) * 64;
    const int m16 = lane & 15, q = lane >> 4;

    // A gather: lane l of wave wv stages rows l and 64+l, k-slice wv*8
    int ra = rt * 128 + lane;       ra = ra < ne ? ra : ne - 1;
    int rb = rt * 128 + 64 + lane;  rb = rb < ne ? rb : ne - 1;
    const unsigned short* ag0 = xb + (size_t)row_token[r0 + ra] * DD + wv * 8;
    const unsigned short* ag1 = xb + (size_t)row_token[r0 + rb] * DD + wv * 8;

    // B stream: swizzled panels, contiguous per wave
    const unsigned short* bg = w1s + (size_t)e * HH * DD + (size_t)nt * (DD >> 5) * 4096
                               + wv * 1024 + lane * 8;

    f32x4 acc[4][4];
    f32x4 zero = {0.f, 0.f, 0.f, 0.f};
    #pragma unroll
    for (int i = 0; i < 4; i++)
        #pragma unroll
        for (int j = 0; j < 4; j++) acc[i][j] = zero;

    kloop_3s<DD / 32>(ag0, ag1, bg, &As[0][0], &Bs[0][0], wv, lane, wr, wc, m16, q, acc);

    const int n0 = nt * 128;
    float b1v[4];
    #pragma unroll
    for (int j = 0; j < 4; j++) b1v[j] = b1[(size_t)e * HH + n0 + wc + j * 16 + m16];
    #pragma unroll
    for (int i = 0; i < 4; i++) {
        #pragma unroll
        for (int rg = 0; rg < 4; rg++) {
            int rr = rt * 128 + wr + i * 16 + q * 4 + rg;
            if (rr < ne) {
                unsigned short* hrow = hbuf + (size_t)(r0 + rr) * HH;
                #pragma unroll
                for (int j = 0; j < 4; j++) {
                    int col = n0 + wc + j * 16 + m16;
                    float v = acc[i][j][rg] + b1v[j];
                    hrow[col] = f2bf(gelu_fast(v));
                }
            }
        }
    }
}

// ---------- GEMM2 (full K=4096): y = h @ w2[e] + b2 + x ----------
// 1-D grid 2048, XCD-grouping decode: 8 nt-blocks sharing one gathered A-panel
// (same rt,e) land on one XCD; rt-neighbors (B-sharers) are g-neighbors there too.
__global__ __launch_bounds__(256) void gemm2_kernel(
        const unsigned short* __restrict__ hbuf, const unsigned short* __restrict__ w2s,
        const float* __restrict__ b2, const float* __restrict__ x,
        const int* __restrict__ offs, const int* __restrict__ row_token,
        float* __restrict__ yp) {
    const int bid = blockIdx.x;
    const int xcd = bid & 7;
    const int nt  = (bid >> 3) & 7;
    const int g   = (bid >> 6) * 8 + xcd;   // [0,256) bijective
    const int rt  = g & 31;
    const int e   = g >> 5;

    const int r0 = offs[e];
    const int ne = offs[e + 1] - r0;
    if (rt * 128 >= ne) return;

    __shared__ __align__(16) unsigned short As[3][4096];
    __shared__ __align__(16) unsigned short Bs[3][4096];

    const int tid = threadIdx.x;
    const int lane = tid & 63;
    const int wv = tid >> 6;
    const int wr = (wv >> 1) * 64, wc = (wv & 1) * 64;
    const int m16 = lane & 15, q = lane >> 4;

    int ra = rt * 128 + lane;       ra = ra < ne ? ra : ne - 1;
    int rb = rt * 128 + 64 + lane;  rb = rb < ne ? rb : ne - 1;
    const unsigned short* ag0 = hbuf + (size_t)(r0 + ra) * HH + wv * 8;
    const unsigned short* ag1 = hbuf + (size_t)(r0 + rb) * HH + wv * 8;

    const unsigned short* bg = w2s + (size_t)e * DD * HH + (size_t)nt * (HH >> 5) * 4096
                               + wv * 1024 + lane * 8;

    f32x4 acc[4][4];
    f32x4 zero = {0.f, 0.f, 0.f, 0.f};
    #pragma unroll
    for (int i = 0; i < 4; i++)
        #pragma unroll
        for (int j = 0; j < 4; j++) acc[i][j] = zero;

    kloop_3s<HH / 32>(ag0, ag1, bg, &As[0][0], &Bs[0][0], wv, lane, wr, wc, m16, q, acc);

    const int n0 = nt * 128;
    float b2v[4];
    #pragma unroll
    for (int j = 0; j < 4; j++) b2v[j] = b2[(size_t)e * DD + n0 + wc + j * 16 + m16];
    #pragma unroll
    for (int i = 0; i < 4; i++) {
        #pragma unroll
        for (int rg = 0; rg < 4; rg++) {
            int rr = rt * 128 + wr + i * 16 + q * 4 + rg;
            if (rr < ne) {
                float* yrow = yp + (size_t)(r0 + rr) * DD;
                int tok = row_token[r0 + rr];
                const float* xrow = x + (size_t)tok * DD;
                #pragma unroll
                for (int j = 0; j < 4; j++) {
                    int col = n0 + wc + j * 16 + m16;
                    yrow[col] = acc[i][j][rg] + b2v[j] + xrow[col];
                }
            }
        }
    }
}

// ---------- LayerNorm + combine ----------
__global__ void ln_combine_kernel(const float* __restrict__ yp,
                                  const int* __restrict__ slot_of,
                                  const int* __restrict__ topk_e, const float* __restrict__ topk_p,
                                  const float* __restrict__ gamma, const float* __restrict__ beta,
                                  float* __restrict__ out) {
    const int t = blockIdx.x;
    const int tid = threadIdx.x;
    __shared__ float ps[8];
    float4 o = {0.f, 0.f, 0.f, 0.f};
    #pragma unroll
    for (int k = 0; k < 2; k++) {
        int row = slot_of[t * 2 + k];
        int e = topk_e[t * 2 + k];
        float p = topk_p[t * 2 + k];
        float4 v = *(const float4*)&yp[(size_t)row * DD + tid * 4];
        float s = v.x + v.y + v.z + v.w;
        float sq = v.x * v.x + v.y * v.y + v.z * v.z + v.w * v.w;
        for (int off = 32; off > 0; off >>= 1) {
            s += __shfl_down(s, off);
            sq += __shfl_down(sq, off);
        }
        if ((tid & 63) == 0) { ps[tid >> 6] = s; ps[4 + (tid >> 6)] = sq; }
        __syncthreads();
        float fs = ps[0] + ps[1] + ps[2] + ps[3];
        float fq = ps[4] + ps[5] + ps[6] + ps[7];
        float mu = fs * (1.0f / DD);
        float var = fq * (1.0f / DD) - mu * mu;
        float rsig = rsqrtf(var + 1e-5f);
        float4 g = *(const float4*)&gamma[(size_t)e * DD + tid * 4];
        float4 bb = *(const float4*)&beta[(size_t)e * DD + tid * 4];
        o.x += p * ((v.x - mu) * rsig * g.x + bb.x);
        o.y += p * ((v.y - mu) * rsig * g.y + bb.y);
        o.z += p * ((v.z - mu) * rsig * g.z + bb.z);
        o.w += p * ((v.w - mu) * rsig * g.w + bb.w);
        __syncthreads();
    }
    *(float4*)&out[(size_t)t * DD + tid * 4] = o;
}

extern "C" void kernel_launch(void* const* d_in, const int* in_sizes, int n_in,
                              void* d_out, int out_size, void* d_ws, size_t ws_size,
                              hipStream_t stream) {
    const float* x     = (const float*)d_in[0];
    const float* rw    = (const float*)d_in[1];
    const float* rb    = (const float*)d_in[2];
    const float* w1    = (const float*)d_in[3];
    const float* b1    = (const float*)d_in[4];
    const float* w2    = (const float*)d_in[5];
    const float* b2    = (const float*)d_in[6];
    const float* gamma = (const float*)d_in[7];
    const float* beta  = (const float*)d_in[8];

    float* out    = (float*)d_out;                 // [T][D]
    float* logits = out + (size_t)TT * DD;         // [T][E]

    char* w = (char*)d_ws;
    int*   counts    = (int*)(w + 0);
    int*   offs      = (int*)(w + 64);
    int*   cursor    = (int*)(w + 128);
    int*   topk_e    = (int*)(w + 4096);
    float* topk_p    = (float*)(w + 36864);
    int*   row_token = (int*)(w + 69632);
    int*   slot_of   = (int*)(w + 102400);
    unsigned short* xb   = (unsigned short*)(w + (size_t)1 * 1048576);
    unsigned short* w1s  = (unsigned short*)(w + (size_t)9 * 1048576);
    unsigned short* w2s  = (unsigned short*)(w + (size_t)73 * 1048576);
    unsigned short* hbuf = (unsigned short*)(w + (size_t)137 * 1048576);
    float*          yp   = (float*)(w + (size_t)1 * 1048576);   // aliases xb+w1s[0:24MB] (dead after gemm1)

    hipMemsetAsync(w, 0, 1024, stream);

    transpose_swz_kernel<<<dim3(HH / 64, DD / 64, NE), 256, 0, stream>>>(w1, w1s, DD, HH);
    transpose_swz_kernel<<<dim3(DD / 64, HH / 64, NE), 256, 0, stream>>>(w2, w2s, HH, DD);
    cvtx_kernel<<<4096, 256, 0, stream>>>(x, xb);
    router_kernel<<<TT, 256, 0, stream>>>(x, rw, rb, logits, topk_e, topk_p, counts);
    prefix_kernel<<<1, 64, 0, stream>>>(counts, offs, cursor);
    scatter_kernel<<<RR / 256, 256, 0, stream>>>(topk_e, cursor, row_token, slot_of);
    gemm1_kernel<<<32 * 32 * NE, 256, 0, stream>>>(xb, w1s, b1, offs, row_token, hbuf);
    gemm2_kernel<<<8 * 32 * NE, 256, 0, stream>>>(hbuf, w2s, b2, x, offs, row_token, yp);
    ln_combine_kernel<<<TT, 256, 0, stream>>>(yp, slot_of, topk_e, topk_p, gamma, beta, out);
}

// Round 7
// 742.142 us; speedup vs baseline: 1.0309x; 1.0309x over previous
//
#include <hip/hip_runtime.h>
#include <math.h>

// Problem constants: E=8, D=1024, H=4096, K=2, B=2, S=2048
#define NE 8
#define DD 1024
#define HH 4096
#define TT 4096          // B*S tokens
#define RR 8192          // TT * K rows

typedef __attribute__((ext_vector_type(8))) short short8;   // 8 bf16 (4 VGPRs)
typedef __attribute__((ext_vector_type(4))) float f32x4;    // MFMA C/D frag

__device__ __forceinline__ unsigned short f2bf(float f) {
    unsigned int u = __float_as_uint(f);
    u += 0x7fffu + ((u >> 16) & 1u);   // RNE
    return (unsigned short)(u >> 16);
}

// Fast GELU (exact-erf form): A&S 7.1.26 branchless erf, max |err| 1.5e-7 —
// far below the bf16 quantization of hbuf. ~13 VALU ops vs ~30 for libm erff.
__device__ __forceinline__ float gelu_fast(float v) {
    float z = fabsf(v) * 0.70710678f;
    float t = __fdividef(1.0f, fmaf(0.3275911f, z, 1.0f));
    float p = fmaf(1.061405429f, t, -1.453152027f);
    p = fmaf(p, t, 1.421413741f);
    p = fmaf(p, t, -0.284496736f);
    p = fmaf(p, t, 0.254829592f);
    p = p * t;
    float erf = fmaf(-p, __expf(-z * z), 1.0f);
    return 0.5f * v * (1.0f + copysignf(erf, v));
}

// async global->LDS, 16B per lane; LDS dest = wave-uniform base + lane*16.
__device__ __forceinline__ void async_copy16(void* lds, const void* g) {
    auto* lp = reinterpret_cast<__attribute__((address_space(3))) unsigned int*>(
        (unsigned int)(unsigned long long)(lds));
    auto* gp = reinterpret_cast<const __attribute__((address_space(1))) unsigned int*>(
        (unsigned long long)(g));
    __builtin_amdgcn_global_load_lds(gp, lp, 16, 0, 0);
}

// ---------------- ws layout (bytes) ----------------
// 0: counts[8]   64: offs[9]   128: cursor[8]   192: ntiles   256: tiles[80]
// 4096   : topk_e  [RR] int
// 36864  : topk_p  [RR] float
// 69632  : row_token[RR] int
// 102400 : slot_of [RR] int
// 1MB    : xb  [TT*DD] bf16 (8MB)   -- yp0 [RR*DD] f32 (32MB) aliases [1,33) after gemm1
// 9MB    : w1s [E][H*D] bf16 swizzled (64MB) -- yp1 aliases [33,65) after gemm1
// 73MB   : w2s [E][D*H] bf16 swizzled (64MB)
// 137MB  : hbuf[RR*HH] bf16 (64MB)              total 201MB

// ---------- x -> bf16 ----------
__global__ void cvtx_kernel(const float* __restrict__ x, unsigned short* __restrict__ xb) {
    size_t i = (size_t)(blockIdx.x * 256 + threadIdx.x) * 4;
    float4 v = *(const float4*)&x[i];
    unsigned int lo = (unsigned int)f2bf(v.x) | ((unsigned int)f2bf(v.y) << 16);
    unsigned int hi = (unsigned int)f2bf(v.z) | ((unsigned int)f2bf(v.w) << 16);
    *(uint2*)&xb[i] = make_uint2(lo, hi);
}

// ---------- weight transpose+convert+swizzle ----------
// src [K][N] f32 -> dst swizzled bf16 panels: [nt=n>>7][kb=k>>5][q=(k>>3)&3][row=n&127][lo=k&7]
// grid (N/64, K/64, E), block 256
__global__ __launch_bounds__(256) void transpose_swz_kernel(const float* __restrict__ src,
        unsigned short* __restrict__ dst, int K, int N) {
    const int e = blockIdx.z;
    src += (size_t)e * K * N;
    dst += (size_t)e * K * N;
    const int c0 = blockIdx.x * 64;   // n base
    const int r0 = blockIdx.y * 64;   // k base
    __shared__ unsigned short t[64][65];
    const int tid = threadIdx.x;
    // read: float4 per thread along N, rows along K
    const int rc4 = (tid & 15) * 4, rr = tid >> 4;
    #pragma unroll
    for (int i = 0; i < 4; i++) {
        int r = rr + i * 16;
        float4 v = *(const float4*)&src[(size_t)(r0 + r) * N + c0 + rc4];
        t[r][rc4]     = f2bf(v.x);
        t[r][rc4 + 1] = f2bf(v.y);
        t[r][rc4 + 2] = f2bf(v.z);
        t[r][rc4 + 3] = f2bf(v.w);
    }
    __syncthreads();
    // write: per wave, one 16B chunk per lane (8 consecutive k for one n) -> 1KB contiguous
    const int n_local = tid & 63;
    const int n = c0 + n_local;
    const int nt = n >> 7, row = n & 127;
    const int Kdiv32 = K >> 5;
    #pragma unroll
    for (int it = 0; it < 2; it++) {
        int dg = (tid >> 6) + 4 * it;              // k-group of 8 within the 64-k tile
        int kb = 2 * blockIdx.y + (dg >> 2);
        int q = dg & 3;
        unsigned short tmp[8];
        #pragma unroll
        for (int i = 0; i < 8; i++) tmp[i] = t[dg * 8 + i][n_local];
        size_t idx = ((((size_t)nt * Kdiv32 + kb) * 4 + q) * 128 + row) * 8;
        *(uint4*)&dst[idx] = *(uint4*)&tmp[0];
    }
}

// ---------- router ----------
__global__ void router_kernel(const float* __restrict__ x, const float* __restrict__ rw,
                              const float* __restrict__ rb, float* __restrict__ logits_out,
                              int* __restrict__ topk_e, float* __restrict__ topk_p,
                              int* __restrict__ counts) {
    const int t = blockIdx.x;
    const int tid = threadIdx.x;
    float4 xv = *(const float4*)&x[(size_t)t * DD + tid * 4];
    const float* rwp = rw + (size_t)(tid * 4) * NE;
    float acc[NE];
    #pragma unroll
    for (int e = 0; e < NE; e++) acc[e] = 0.f;
    float xs[4] = {xv.x, xv.y, xv.z, xv.w};
    #pragma unroll
    for (int i = 0; i < 4; i++) {
        #pragma unroll
        for (int e = 0; e < NE; e++) acc[e] += xs[i] * rwp[i * NE + e];
    }
    #pragma unroll
    for (int e = 0; e < NE; e++) {
        float v = acc[e];
        for (int off = 32; off > 0; off >>= 1) v += __shfl_down(v, off);
        acc[e] = v;
    }
    __shared__ float part[4][NE];
    if ((tid & 63) == 0) {
        #pragma unroll
        for (int e = 0; e < NE; e++) part[tid >> 6][e] = acc[e];
    }
    __syncthreads();
    if (tid == 0) {
        float lg[NE];
        #pragma unroll
        for (int e = 0; e < NE; e++)
            lg[e] = part[0][e] + part[1][e] + part[2][e] + part[3][e] + rb[e];
        #pragma unroll
        for (int e = 0; e < NE; e++) logits_out[(size_t)t * NE + e] = lg[e];
        float m = lg[0];
        #pragma unroll
        for (int e = 1; e < NE; e++) m = fmaxf(m, lg[e]);
        float pr[NE];
        #pragma unroll
        for (int e = 0; e < NE; e++) pr[e] = __expf(lg[e] - m);
        int i0 = 0;
        #pragma unroll
        for (int e = 1; e < NE; e++) if (pr[e] > pr[i0]) i0 = e;
        int i1 = (i0 == 0) ? 1 : 0;
        #pragma unroll
        for (int e = 0; e < NE; e++) if (e != i0 && pr[e] > pr[i1]) i1 = e;
        float p0 = pr[i0], p1 = pr[i1];
        float inv = 1.f / (p0 + p1);
        topk_e[t * 2] = i0;  topk_e[t * 2 + 1] = i1;
        topk_p[t * 2] = p0 * inv;  topk_p[t * 2 + 1] = p1 * inv;
        atomicAdd(&counts[i0], 1);
        atomicAdd(&counts[i1], 1);
    }
}

// ---------- prefix + tile-list build ----------
// tiles[t] = (e<<6)|rt for every needed 128-row tile; ntiles = count (<= 72).
// Removes the 75% dead blocks of the old rt<32 worst-case grids.
__global__ void prefix_kernel(const int* __restrict__ counts, int* __restrict__ offs,
                              int* __restrict__ cursor, int* __restrict__ ntiles,
                              int* __restrict__ tiles) {
    if (threadIdx.x == 0) {
        int a = 0;
        for (int e = 0; e < NE; e++) { offs[e] = a; cursor[e] = a; a += counts[e]; }
        offs[NE] = a;
        int tc = 0;
        for (int e = 0; e < NE; e++) {
            int ne = offs[e + 1] - offs[e];
            int nt = (ne + 127) >> 7;
            for (int r = 0; r < nt; r++) tiles[tc++] = (e << 6) | r;
        }
        ntiles[0] = tc;
    }
}

__global__ void scatter_kernel(const int* __restrict__ topk_e, int* __restrict__ cursor,
                               int* __restrict__ row_token, int* __restrict__ slot_of) {
    int i = blockIdx.x * 256 + threadIdx.x;   // i = t*2+k
    int e = topk_e[i];
    int pos = atomicAdd(&cursor[e], 1);
    row_token[pos] = i >> 1;
    slot_of[i] = pos;
}

// ---------- shared MFMA compute step (one BK=32 tile from one LDS buffer) ----------
__device__ __forceinline__ void mfma_step(const unsigned short* Ab, const unsigned short* Bb,
        int wr, int wc, int m16, int q, f32x4 (&acc)[4][4]) {
    short8 af[4], bfr[4];
    #pragma unroll
    for (int i = 0; i < 4; i++) af[i] = *(const short8*)&Ab[q * 1024 + (wr + i * 16 + m16) * 8];
    #pragma unroll
    for (int j = 0; j < 4; j++) bfr[j] = *(const short8*)&Bb[q * 1024 + (wc + j * 16 + m16) * 8];
    #pragma unroll
    for (int i = 0; i < 4; i++)
        #pragma unroll
        for (int j = 0; j < 4; j++)
            acc[i][j] = __builtin_amdgcn_mfma_f32_16x16x32_bf16(af[i], bfr[j], acc[i][j], 0, 0, 0);
}

// ---------- 3-stage pipelined K-loop (T3+T4: counted vmcnt, raw barriers) ----------
// Tile t lives in buffer t%3. Per tile each thread issues 4 global_load_lds.
// Steady state keeps 2 tiles (8 loads) in flight across barriers; vmcnt never 0 in loop.
// Correctness: stage(t+2) targets buf (t-1)%3, freed by the previous iteration's
// post-compute barrier; per-wave vmcnt(8) (FIFO, so tile t's loads done) + s_barrier
// makes completion block-wide before any ds_read. NK >= 3.
template <int NK>
__device__ __forceinline__ void kloop_3s(
        const unsigned short* ag0, const unsigned short* ag1, const unsigned short* bg,
        unsigned short* As, unsigned short* Bs,   // each [3][4096] shorts, buf stride 4096
        int wv, int lane, int wr, int wc, int m16, int q, f32x4 (&acc)[4][4]) {
    unsigned short* alA = As + wv * 1024 + lane * 8;
    unsigned short* blB = Bs + wv * 1024 + lane * 8;

    // prologue: stage tiles 0,1 -> buf0,1 (8 loads in flight)
    #pragma unroll
    for (int p = 0; p < 2; ++p) {
        async_copy16(alA + p * 4096, ag0); async_copy16(alA + p * 4096 + 512, ag1);
        async_copy16(blB + p * 4096, bg);  async_copy16(blB + p * 4096 + 512, bg + 512);
        ag0 += 32; ag1 += 32; bg += 4096;
    }

    int cOff = 0;            // (t%3)*4096
    int sOff = 2 * 4096;     // ((t+2)%3)*4096
    #pragma unroll 1
    for (int t = 0; t < NK - 2; ++t) {
        async_copy16(alA + sOff, ag0); async_copy16(alA + sOff + 512, ag1);
        async_copy16(blB + sOff, bg);  async_copy16(blB + sOff + 512, bg + 512);
        ag0 += 32; ag1 += 32; bg += 4096;
        asm volatile("s_waitcnt vmcnt(8)" ::: "memory");   // tile t landed (2 tiles in flight)
        __builtin_amdgcn_s_barrier();
        mfma_step(As + cOff, Bs + cOff, wr, wc, m16, q, acc);
        __builtin_amdgcn_s_barrier();                      // all waves done reading buf t%3
        sOff = cOff;                                       // (t+3)%3 == t%3
        cOff += 4096; if (cOff == 3 * 4096) cOff = 0;      // (t+1)%3
    }
    // tail: tiles NK-2 (buf cOff), NK-1 already staged; drain 4 -> 0
    asm volatile("s_waitcnt vmcnt(4)" ::: "memory");
    __builtin_amdgcn_s_barrier();
    mfma_step(As + cOff, Bs + cOff, wr, wc, m16, q, acc);
    cOff += 4096; if (cOff == 3 * 4096) cOff = 0;
    asm volatile("s_waitcnt vmcnt(0)" ::: "memory");
    __builtin_amdgcn_s_barrier();
    mfma_step(As + cOff, Bs + cOff, wr, wc, m16, q, acc);
}

// ---------- GEMM1: h = gelu(X_e @ w1[e] + b1[e]) ----------
// tile 128x128, BK=32, 3-stage pipelined staging.
// grid = 72*32 via tile list: bid = t*32 + nt. All launched blocks (except
// t >= ntiles, <= 8) do real work. B-sharers (same nt, tiles of one expert)
// keep bid%8 = nt%8 -> same XCD under round-robin dispatch (T1).
__global__ __launch_bounds__(256) void gemm1_kernel(
        const unsigned short* __restrict__ xb, const unsigned short* __restrict__ w1s,
        const float* __restrict__ b1, const int* __restrict__ offs,
        const int* __restrict__ row_token, const int* __restrict__ ntiles,
        const int* __restrict__ tiles, unsigned short* __restrict__ hbuf) {
    const int bid = blockIdx.x;
    const int t = bid >> 5;
    const int nt = bid & 31;
    if (t >= ntiles[0]) return;
    const int pk = tiles[t];
    const int e = pk >> 6, rt = pk & 63;

    const int r0 = offs[e];
    const int ne = offs[e + 1] - r0;

    __shared__ __align__(16) unsigned short As[3][4096];
    __shared__ __align__(16) unsigned short Bs[3][4096];

    const int tid = threadIdx.x;
    const int lane = tid & 63;
    const int wv = tid >> 6;
    const int wr = (wv >> 1) * 64, wc = (wv & 1) * 64;
    const int m16 = lane & 15, q = lane >> 4;

    // A gather: lane l of wave wv stages rows l and 64+l, k-slice wv*8
    int ra = rt * 128 + lane;       ra = ra < ne ? ra : ne - 1;
    int rb = rt * 128 + 64 + lane;  rb = rb < ne ? rb : ne - 1;
    const unsigned short* ag0 = xb + (size_t)row_token[r0 + ra] * DD + wv * 8;
    const unsigned short* ag1 = xb + (size_t)row_token[r0 + rb] * DD + wv * 8;

    // B stream: swizzled panels, contiguous per wave
    const unsigned short* bg = w1s + (size_t)e * HH * DD + (size_t)nt * (DD >> 5) * 4096
                               + wv * 1024 + lane * 8;

    f32x4 acc[4][4];
    f32x4 zero = {0.f, 0.f, 0.f, 0.f};
    #pragma unroll
    for (int i = 0; i < 4; i++)
        #pragma unroll
        for (int j = 0; j < 4; j++) acc[i][j] = zero;

    kloop_3s<DD / 32>(ag0, ag1, bg, &As[0][0], &Bs[0][0], wv, lane, wr, wc, m16, q, acc);

    const int n0 = nt * 128;
    float b1v[4];
    #pragma unroll
    for (int j = 0; j < 4; j++) b1v[j] = b1[(size_t)e * HH + n0 + wc + j * 16 + m16];
    #pragma unroll
    for (int i = 0; i < 4; i++) {
        #pragma unroll
        for (int rg = 0; rg < 4; rg++) {
            int rr = rt * 128 + wr + i * 16 + q * 4 + rg;
            if (rr < ne) {
                unsigned short* hrow = hbuf + (size_t)(r0 + rr) * HH;
                #pragma unroll
                for (int j = 0; j < 4; j++) {
                    int col = n0 + wc + j * 16 + m16;
                    float v = acc[i][j][rg] + b1v[j];
                    hrow[col] = f2bf(gelu_fast(v));
                }
            }
        }
    }
}

// ---------- GEMM2 (split-K=2): y_c = h[:, kc] @ w2[e][kc, :] (+ b2 + x on chunk 0) ----------
// grid = 144*8 = 1152 via tile list. Decode keeps all 8 nt-sharers of one
// (t,chunk) A-panel at equal bid%8 -> same XCD (T1): w = (bid>>6)*8 + (bid&7),
// nt = (bid>>3)&7, t = w>>1, chunk = w&1. Bijective for grid 18*64.
__global__ __launch_bounds__(256) void gemm2_kernel(
        const unsigned short* __restrict__ hbuf, const unsigned short* __restrict__ w2s,
        const float* __restrict__ b2, const float* __restrict__ x,
        const int* __restrict__ offs, const int* __restrict__ row_token,
        const int* __restrict__ ntiles, const int* __restrict__ tiles,
        float* __restrict__ yp0, float* __restrict__ yp1) {
    const int bid = blockIdx.x;
    const int nt = (bid >> 3) & 7;
    const int w = (bid >> 6) * 8 + (bid & 7);
    const int t = w >> 1;
    const int chunk = w & 1;
    if (t >= ntiles[0]) return;
    const int pk = tiles[t];
    const int e = pk >> 6, rt = pk & 63;

    const int r0 = offs[e];
    const int ne = offs[e + 1] - r0;
    const int kbase = chunk * (HH / 2);
    float* ybuf = chunk ? yp1 : yp0;

    __shared__ __align__(16) unsigned short As[3][4096];
    __shared__ __align__(16) unsigned short Bs[3][4096];

    const int tid = threadIdx.x;
    const int lane = tid & 63;
    const int wv = tid >> 6;
    const int wr = (wv >> 1) * 64, wc = (wv & 1) * 64;
    const int m16 = lane & 15, q = lane >> 4;

    int ra = rt * 128 + lane;       ra = ra < ne ? ra : ne - 1;
    int rb = rt * 128 + 64 + lane;  rb = rb < ne ? rb : ne - 1;
    const unsigned short* ag0 = hbuf + (size_t)(r0 + ra) * HH + kbase + wv * 8;
    const unsigned short* ag1 = hbuf + (size_t)(r0 + rb) * HH + kbase + wv * 8;

    const unsigned short* bg = w2s + (size_t)e * DD * HH + (size_t)nt * (HH >> 5) * 4096
                               + (size_t)(kbase >> 5) * 4096 + wv * 1024 + lane * 8;

    f32x4 acc[4][4];
    f32x4 zero = {0.f, 0.f, 0.f, 0.f};
    #pragma unroll
    for (int i = 0; i < 4; i++)
        #pragma unroll
        for (int j = 0; j < 4; j++) acc[i][j] = zero;

    kloop_3s<(HH / 2) / 32>(ag0, ag1, bg, &As[0][0], &Bs[0][0], wv, lane, wr, wc, m16, q, acc);

    const int n0 = nt * 128;
    float b2v[4] = {0.f, 0.f, 0.f, 0.f};
    if (chunk == 0) {
        #pragma unroll
        for (int j = 0; j < 4; j++) b2v[j] = b2[(size_t)e * DD + n0 + wc + j * 16 + m16];
    }
    #pragma unroll
    for (int i = 0; i < 4; i++) {
        #pragma unroll
        for (int rg = 0; rg < 4; rg++) {
            int rr = rt * 128 + wr + i * 16 + q * 4 + rg;
            if (rr < ne) {
                float* yrow = ybuf + (size_t)(r0 + rr) * DD;
                if (chunk == 0) {
                    int tok = row_token[r0 + rr];
                    const float* xrow = x + (size_t)tok * DD;
                    #pragma unroll
                    for (int j = 0; j < 4; j++) {
                        int col = n0 + wc + j * 16 + m16;
                        yrow[col] = acc[i][j][rg] + b2v[j] + xrow[col];
                    }
                } else {
                    #pragma unroll
                    for (int j = 0; j < 4; j++) {
                        int col = n0 + wc + j * 16 + m16;
                        yrow[col] = acc[i][j][rg];
                    }
                }
            }
        }
    }
}

// ---------- LayerNorm + combine (sums split-K partials, no atomics) ----------
__global__ void ln_combine_kernel(const float* __restrict__ yp0, const float* __restrict__ yp1,
                                  const int* __restrict__ slot_of,
                                  const int* __restrict__ topk_e, const float* __restrict__ topk_p,
                                  const float* __restrict__ gamma, const float* __restrict__ beta,
                                  float* __restrict__ out) {
    const int t = blockIdx.x;
    const int tid = threadIdx.x;
    __shared__ float ps[8];
    float4 o = {0.f, 0.f, 0.f, 0.f};
    #pragma unroll
    for (int k = 0; k < 2; k++) {
        int row = slot_of[t * 2 + k];
        int e = topk_e[t * 2 + k];
        float p = topk_p[t * 2 + k];
        float4 v0 = *(const float4*)&yp0[(size_t)row * DD + tid * 4];
        float4 v1 = *(const float4*)&yp1[(size_t)row * DD + tid * 4];
        float4 v = {v0.x + v1.x, v0.y + v1.y, v0.z + v1.z, v0.w + v1.w};
        float s = v.x + v.y + v.z + v.w;
        float sq = v.x * v.x + v.y * v.y + v.z * v.z + v.w * v.w;
        for (int off = 32; off > 0; off >>= 1) {
            s += __shfl_down(s, off);
            sq += __shfl_down(sq, off);
        }
        if ((tid & 63) == 0) { ps[tid >> 6] = s; ps[4 + (tid >> 6)] = sq; }
        __syncthreads();
        float fs = ps[0] + ps[1] + ps[2] + ps[3];
        float fq = ps[4] + ps[5] + ps[6] + ps[7];
        float mu = fs * (1.0f / DD);
        float var = fq * (1.0f / DD) - mu * mu;
        float rsig = rsqrtf(var + 1e-5f);
        float4 g = *(const float4*)&gamma[(size_t)e * DD + tid * 4];
        float4 bb = *(const float4*)&beta[(size_t)e * DD + tid * 4];
        o.x += p * ((v.x - mu) * rsig * g.x + bb.x);
        o.y += p * ((v.y - mu) * rsig * g.y + bb.y);
        o.z += p * ((v.z - mu) * rsig * g.z + bb.z);
        o.w += p * ((v.w - mu) * rsig * g.w + bb.w);
        __syncthreads();
    }
    *(float4*)&out[(size_t)t * DD + tid * 4] = o;
}

extern "C" void kernel_launch(void* const* d_in, const int* in_sizes, int n_in,
                              void* d_out, int out_size, void* d_ws, size_t ws_size,
                              hipStream_t stream) {
    const float* x     = (const float*)d_in[0];
    const float* rw    = (const float*)d_in[1];
    const float* rb    = (const float*)d_in[2];
    const float* w1    = (const float*)d_in[3];
    const float* b1    = (const float*)d_in[4];
    const float* w2    = (const float*)d_in[5];
    const float* b2    = (const float*)d_in[6];
    const float* gamma = (const float*)d_in[7];
    const float* beta  = (const float*)d_in[8];

    float* out    = (float*)d_out;                 // [T][D]
    float* logits = out + (size_t)TT * DD;         // [T][E]

    char* w = (char*)d_ws;
    int*   counts    = (int*)(w + 0);
    int*   offs      = (int*)(w + 64);
    int*   cursor    = (int*)(w + 128);
    int*   ntiles    = (int*)(w + 192);
    int*   tiles     = (int*)(w + 256);
    int*   topk_e    = (int*)(w + 4096);
    float* topk_p    = (float*)(w + 36864);
    int*   row_token = (int*)(w + 69632);
    int*   slot_of   = (int*)(w + 102400);
    unsigned short* xb   = (unsigned short*)(w + (size_t)1 * 1048576);
    unsigned short* w1s  = (unsigned short*)(w + (size_t)9 * 1048576);
    unsigned short* w2s  = (unsigned short*)(w + (size_t)73 * 1048576);
    unsigned short* hbuf = (unsigned short*)(w + (size_t)137 * 1048576);
    float*          yp0  = (float*)(w + (size_t)1 * 1048576);   // aliases xb (dead after gemm1)
    float*          yp1  = (float*)(w + (size_t)33 * 1048576);  // aliases w1s (dead after gemm1)

    hipMemsetAsync(w, 0, 1024, stream);

    transpose_swz_kernel<<<dim3(HH / 64, DD / 64, NE), 256, 0, stream>>>(w1, w1s, DD, HH);
    transpose_swz_kernel<<<dim3(DD / 64, HH / 64, NE), 256, 0, stream>>>(w2, w2s, HH, DD);
    cvtx_kernel<<<4096, 256, 0, stream>>>(x, xb);
    router_kernel<<<TT, 256, 0, stream>>>(x, rw, rb, logits, topk_e, topk_p, counts);
    prefix_kernel<<<1, 64, 0, stream>>>(counts, offs, cursor, ntiles, tiles);
    scatter_kernel<<<RR / 256, 256, 0, stream>>>(topk_e, cursor, row_token, slot_of);
    gemm1_kernel<<<72 * 32, 256, 0, stream>>>(xb, w1s, b1, offs, row_token, ntiles, tiles, hbuf);
    gemm2_kernel<<<18 * 64, 256, 0, stream>>>(hbuf, w2s, b2, x, offs, row_token, ntiles, tiles, yp0, yp1);
    ln_combine_kernel<<<TT, 256, 0, stream>>>(yp0, yp1, slot_of, topk_e, topk_p, gamma, beta, out);
}